// Round 2
// baseline (7461.852 us; speedup 1.0000x reference)
//
#include <hip/hip_runtime.h>
#include <hip/hip_bf16.h>

// VQ-VAE vector quantizer forward, MI355X.
// inputs:  d_in[0] = inputs  [128*512*256] f32  (N=65536 tokens x D=256)
//          d_in[1] = embedding [1024*256] f32   (K=1024 codes x D=256)
// outputs (concat f32): [0] vq_loss | [1..16777216] quantized_st |
//          [16777217] perplexity | [16777218..] encodings one-hot [65536*1024]

constexpr int NTOK = 65536;
constexpr int D    = 256;
constexpr int K    = 1024;

// ---------------- kernel 0: ||e_k||^2 ----------------
__global__ __launch_bounds__(256) void e2_kernel(
    const float* __restrict__ emb, float* __restrict__ e2) {
  const int lane = threadIdx.x & 63;
  const int gw   = (int)((blockIdx.x * blockDim.x + threadIdx.x) >> 6); // 64 waves
  for (int k = gw; k < K; k += 64) {
    float4 v = reinterpret_cast<const float4*>(emb + (size_t)k * D)[lane];
    float s = v.x * v.x + v.y * v.y + v.z * v.z + v.w * v.w;
    #pragma unroll
    for (int m = 1; m < 64; m <<= 1) s += __shfl_xor(s, m);
    if (lane == 0) e2[k] = s;
  }
}

// ---------------- kernel 1: argmin over codes ----------------
// 4 lanes per token, each lane holds a 64-float quarter of the token row in
// VGPRs (16 x float4). Loop over all 1024 codes, 2 at a time; partial dots
// combined across the 4 lanes with shfl_xor. dist = ||e||^2 - 2*dot
// (||x||^2 dropped: constant per row, argmin-invariant). Strict < keeps the
// first (lowest-index) minimum, matching jnp.argmin.
__global__ __launch_bounds__(256, 4) void argmin_kernel(
    const float* __restrict__ x, const float* __restrict__ emb,
    const float* __restrict__ e2, int* __restrict__ out_idx) {
  const int lane = threadIdx.x & 63;
  const int wib  = threadIdx.x >> 6;   // wave in block: 0..3
  const int tsub = lane >> 2;          // token within wave: 0..15
  const int dq   = lane & 3;           // d-quarter: 0..3
  const int tok  = (int)blockIdx.x * 64 + wib * 16 + tsub;

  const float4* xr =
      reinterpret_cast<const float4*>(x + (size_t)tok * D) + dq * 16;
  float4 xq[16];
  #pragma unroll
  for (int i = 0; i < 16; ++i) xq[i] = xr[i];

  const float4* ebase = reinterpret_cast<const float4*>(emb) + dq * 16;

  float best = 3.4e38f;
  int   bidx = 0;
  for (int k = 0; k < K; k += 2) {
    const float4* e0 = ebase + (size_t)k * (D / 4);
    const float4* e1 = e0 + (D / 4);
    float a0 = 0.f, a1 = 0.f, b0 = 0.f, b1 = 0.f;
    #pragma unroll
    for (int i = 0; i < 16; ++i) {
      float4 xa = xq[i];
      float4 ea = e0[i];
      float4 eb = e1[i];
      a0 = fmaf(xa.x, ea.x, a0);
      a1 = fmaf(xa.y, ea.y, a1);
      a0 = fmaf(xa.z, ea.z, a0);
      a1 = fmaf(xa.w, ea.w, a1);
      b0 = fmaf(xa.x, eb.x, b0);
      b1 = fmaf(xa.y, eb.y, b1);
      b0 = fmaf(xa.z, eb.z, b0);
      b1 = fmaf(xa.w, eb.w, b1);
    }
    float dot0 = a0 + a1;
    float dot1 = b0 + b1;
    // combine the 4 d-quarters (lanes tsub*4 .. tsub*4+3)
    dot0 += __shfl_xor(dot0, 1);
    dot0 += __shfl_xor(dot0, 2);
    dot1 += __shfl_xor(dot1, 1);
    dot1 += __shfl_xor(dot1, 2);
    float dist0 = fmaf(-2.f, dot0, e2[k]);
    float dist1 = fmaf(-2.f, dot1, e2[k + 1]);
    if (dist0 < best) { best = dist0; bidx = k; }
    if (dist1 < best) { best = dist1; bidx = k + 1; }
  }
  if (dq == 0) out_idx[tok] = bidx;
}

// ---------------- kernel 2: gather + one-hot + loss partials + histogram ----
// One wave per token (grid-stride): 64 lanes x float4 = 256 floats per row.
__global__ __launch_bounds__(256) void output_kernel(
    const float* __restrict__ x, const float* __restrict__ emb,
    const int* __restrict__ idx, float* __restrict__ qout,
    float* __restrict__ enc, int* __restrict__ hist,
    double* __restrict__ lossacc) {
  const int lane = threadIdx.x & 63;
  const int gw   = (int)((blockIdx.x * 256 + threadIdx.x) >> 6); // 0..8191
  float lsum = 0.f;
  for (int tok = gw; tok < NTOK; tok += 8192) {
    const int ki = idx[tok];
    float4 xv = reinterpret_cast<const float4*>(x + (size_t)tok * D)[lane];
    float4 ev = reinterpret_cast<const float4*>(emb + (size_t)ki * D)[lane];
    // straight-through output computed literally as x + (q - x) like reference
    float dx = ev.x - xv.x, dy = ev.y - xv.y, dz = ev.z - xv.z,
          dw = ev.w - xv.w;
    float4 q;
    q.x = xv.x + dx; q.y = xv.y + dy; q.z = xv.z + dz; q.w = xv.w + dw;
    reinterpret_cast<float4*>(qout + (size_t)tok * D)[lane] = q;
    lsum += dx * dx + dy * dy + dz * dz + dw * dw;
    // one-hot row: 1024 floats = 4 coalesced float4 stores per lane
    float4* erow = reinterpret_cast<float4*>(enc + (size_t)tok * K);
    #pragma unroll
    for (int r = 0; r < 4; ++r) {
      const int fi = r * 64 + lane;
      float4 z;
      z.x = (fi * 4 + 0 == ki) ? 1.f : 0.f;
      z.y = (fi * 4 + 1 == ki) ? 1.f : 0.f;
      z.z = (fi * 4 + 2 == ki) ? 1.f : 0.f;
      z.w = (fi * 4 + 3 == ki) ? 1.f : 0.f;
      erow[fi] = z;
    }
    if (lane == 0) atomicAdd(&hist[ki], 1);
  }
  // block-reduce loss partials, one double atomic per block
  #pragma unroll
  for (int m = 1; m < 64; m <<= 1) lsum += __shfl_xor(lsum, m);
  __shared__ float wsum[4];
  if (lane == 0) wsum[threadIdx.x >> 6] = lsum;
  __syncthreads();
  if (threadIdx.x == 0) {
    double t = (double)wsum[0] + (double)wsum[1] + (double)wsum[2] +
               (double)wsum[3];
    atomicAdd(lossacc, t);
  }
}

// ---------------- kernel 3: finalize scalars ----------------
__global__ __launch_bounds__(256) void finalize_kernel(
    const int* __restrict__ hist, const double* __restrict__ lossacc,
    float* __restrict__ out_loss, float* __restrict__ out_perp) {
  const int lane = threadIdx.x & 63;
  float part = 0.f;
  for (int k = threadIdx.x; k < K; k += 256) {
    float p = (float)hist[k] * (1.0f / 65536.0f);
    part += p * logf(p + 1e-10f);
  }
  #pragma unroll
  for (int m = 1; m < 64; m <<= 1) part += __shfl_xor(part, m);
  __shared__ float wsum[4];
  if (lane == 0) wsum[threadIdx.x >> 6] = part;
  __syncthreads();
  if (threadIdx.x == 0) {
    float ent = wsum[0] + wsum[1] + wsum[2] + wsum[3];
    out_loss[0] = 0.25f * (float)(lossacc[0] * (1.0 / 16777216.0));
    out_perp[0] = expf(-ent);
  }
}

extern "C" void kernel_launch(void* const* d_in, const int* in_sizes, int n_in,
                              void* d_out, int out_size, void* d_ws,
                              size_t ws_size, hipStream_t stream) {
  const float* x   = (const float*)d_in[0];
  const float* emb = (const float*)d_in[1];
  float* out       = (float*)d_out;

  float* loss_out = out;                        // [0]
  float* q_out    = out + 1;                    // 16777216 elements
  float* perp_out = out + 1 + (size_t)NTOK * D; // [16777217]
  float* enc_out  = perp_out + 1;               // 67108864 elements

  char*   wsb  = (char*)d_ws;
  int*    idx  = (int*)wsb;                     // 65536 ints   @ 0
  float*  e2   = (float*)(wsb + 262144);        // 1024 f       @ 262144
  int*    hist = (int*)(wsb + 266240);          // 1024 int     @ 266240
  double* acc  = (double*)(wsb + 270336);       // 1 double     @ 270336

  // zero histogram + loss accumulator (ws is poisoned 0xAA before each call)
  hipMemsetAsync(wsb + 266240, 0, 8192, stream);

  e2_kernel<<<16, 256, 0, stream>>>(emb, e2);
  argmin_kernel<<<NTOK / 64, 256, 0, stream>>>(x, emb, e2, idx);
  output_kernel<<<2048, 256, 0, stream>>>(x, emb, idx, q_out, enc_out, hist,
                                          acc);
  finalize_kernel<<<1, 256, 0, stream>>>(hist, acc, loss_out, perp_out);
}

// Round 4
// 1120.806 us; speedup vs baseline: 6.6576x; 6.6576x over previous
//
#include <hip/hip_runtime.h>
#include <hip/hip_bf16.h>

// VQ-VAE vector quantizer forward, MI355X.
// inputs:  d_in[0] = inputs  [128*512*256] f32  (N=65536 tokens x D=256)
//          d_in[1] = embedding [1024*256] f32   (K=1024 codes x D=256)
// outputs (concat f32): [0] vq_loss | [1..16777216] quantized_st |
//          [16777217] perplexity | [16777218..] encodings one-hot [65536*1024]

constexpr int NTOK = 65536;
constexpr int D    = 256;
constexpr int K    = 1024;

// ---------------- kernel 0: ||e_k||^2 ----------------
__global__ __launch_bounds__(256) void e2_kernel(
    const float* __restrict__ emb, float* __restrict__ e2) {
  const int lane = threadIdx.x & 63;
  const int gw   = (int)((blockIdx.x * blockDim.x + threadIdx.x) >> 6); // 64 waves
  for (int k = gw; k < K; k += 64) {
    float4 v = reinterpret_cast<const float4*>(emb + (size_t)k * D)[lane];
    float s = v.x * v.x + v.y * v.y + v.z * v.z + v.w * v.w;
    #pragma unroll
    for (int m = 1; m < 64; m <<= 1) s += __shfl_xor(s, m);
    if (lane == 0) e2[k] = s;
  }
}

// ---------------- kernel 1: tiled distance GEMM + fused argmin ----------------
// Block: 64 tokens x 1024 codes (16 chunks of 64). 256 threads = 16x16 grid,
// micro-tile 4 tokens x 4 codes. LDS: xT[256][64] + eT[256][64] = 128 KB.
// dist = ||e||^2 - 2*dot (||x||^2 dropped: argmin-invariant per token).
// Strict < with ascending code order == jnp.argmin first-min tie-break.
__global__ __launch_bounds__(256, 1) void argmin_kernel(
    const float* __restrict__ x, const float* __restrict__ emb,
    const float* __restrict__ e2, int* __restrict__ out_idx) {
  __shared__ float xs[D * 64];  // xT[d][t], stride 64 floats
  __shared__ float es[D * 64];  // eT[d][c], stride 64 floats
  const int tid  = (int)threadIdx.x;
  const int tx   = tid & 15;   // code group within chunk  (codes tx*4..+3)
  const int ty   = tid >> 4;   // token group within block (tokens ty*4..+3)
  const int tok0 = (int)blockIdx.x * 64;

  // ---- stage x tile, transposed; lane<->column mapping keeps LDS writes
  //      conflict-free (bank = t%32, 2 lanes/bank = free) ----
  {
    const int t = tid & 63;
    const int g = tid >> 6;
    const float4* xg =
        reinterpret_cast<const float4*>(x) + (size_t)(tok0 + t) * 64;
    #pragma unroll
    for (int p = 0; p < 16; ++p) {
      const int d4 = p * 4 + g;
      float4 v = xg[d4];
      xs[(d4 * 4 + 0) * 64 + t] = v.x;
      xs[(d4 * 4 + 1) * 64 + t] = v.y;
      xs[(d4 * 4 + 2) * 64 + t] = v.z;
      xs[(d4 * 4 + 3) * 64 + t] = v.w;
    }
  }

  float best[4];
  int   bidx[4];
  #pragma unroll
  for (int t = 0; t < 4; ++t) { best[t] = 3.4e38f; bidx[t] = 0; }

  for (int ch = 0; ch < 16; ++ch) {
    if (ch) __syncthreads();  // previous chunk's compute done before overwrite
    // ---- stage e chunk (64 codes), transposed, conflict-free writes ----
    {
      const int c = tid & 63;
      const int g = tid >> 6;
      const float4* eg = reinterpret_cast<const float4*>(emb) +
                         (size_t)(ch * 64 + c) * 64;
      #pragma unroll
      for (int p = 0; p < 16; ++p) {
        const int d4 = p * 4 + g;
        float4 v = eg[d4];
        es[(d4 * 4 + 0) * 64 + c] = v.x;
        es[(d4 * 4 + 1) * 64 + c] = v.y;
        es[(d4 * 4 + 2) * 64 + c] = v.z;
        es[(d4 * 4 + 3) * 64 + c] = v.w;
      }
    }
    __syncthreads();

    float acc[4][4];
    #pragma unroll
    for (int a = 0; a < 4; ++a) {
      #pragma unroll
      for (int b = 0; b < 4; ++b) acc[a][b] = 0.f;
    }

    #pragma unroll 4
    for (int d = 0; d < D; ++d) {
      const float4 xv =
          *reinterpret_cast<const float4*>(&xs[d * 64 + ty * 4]);
      const float4 ev =
          *reinterpret_cast<const float4*>(&es[d * 64 + tx * 4]);
      acc[0][0] = fmaf(xv.x, ev.x, acc[0][0]);
      acc[0][1] = fmaf(xv.x, ev.y, acc[0][1]);
      acc[0][2] = fmaf(xv.x, ev.z, acc[0][2]);
      acc[0][3] = fmaf(xv.x, ev.w, acc[0][3]);
      acc[1][0] = fmaf(xv.y, ev.x, acc[1][0]);
      acc[1][1] = fmaf(xv.y, ev.y, acc[1][1]);
      acc[1][2] = fmaf(xv.y, ev.z, acc[1][2]);
      acc[1][3] = fmaf(xv.y, ev.w, acc[1][3]);
      acc[2][0] = fmaf(xv.z, ev.x, acc[2][0]);
      acc[2][1] = fmaf(xv.z, ev.y, acc[2][1]);
      acc[2][2] = fmaf(xv.z, ev.z, acc[2][2]);
      acc[2][3] = fmaf(xv.z, ev.w, acc[2][3]);
      acc[3][0] = fmaf(xv.w, ev.x, acc[3][0]);
      acc[3][1] = fmaf(xv.w, ev.y, acc[3][1]);
      acc[3][2] = fmaf(xv.w, ev.z, acc[3][2]);
      acc[3][3] = fmaf(xv.w, ev.w, acc[3][3]);
    }

    // fold distances, running argmin (ascending code order)
    #pragma unroll
    for (int j = 0; j < 4; ++j) {
      const int  code = ch * 64 + tx * 4 + j;
      const float e2v = e2[code];
      #pragma unroll
      for (int t = 0; t < 4; ++t) {
        const float dist = fmaf(-2.f, acc[t][j], e2v);
        if (dist < best[t]) { best[t] = dist; bidx[t] = code; }
      }
    }
  }

  // cross-tx reduction: 16-lane groups, (dist, idx) with first-min tie-break
  #pragma unroll
  for (int m = 1; m < 16; m <<= 1) {
    #pragma unroll
    for (int t = 0; t < 4; ++t) {
      const float ob = __shfl_xor(best[t], m);
      const int   oi = __shfl_xor(bidx[t], m);
      if (ob < best[t] || (ob == best[t] && oi < bidx[t])) {
        best[t] = ob;
        bidx[t] = oi;
      }
    }
  }
  if (tx == 0) {
    #pragma unroll
    for (int t = 0; t < 4; ++t) out_idx[tok0 + ty * 4 + t] = bidx[t];
  }
}

// ---------------- kernel 2: gather + one-hot + loss partials + histogram ----
// One wave per token (grid-stride): 64 lanes x float4 = 256 floats per row.
__global__ __launch_bounds__(256) void output_kernel(
    const float* __restrict__ x, const float* __restrict__ emb,
    const int* __restrict__ idx, float* __restrict__ qout,
    float* __restrict__ enc, int* __restrict__ hist,
    double* __restrict__ lossacc) {
  const int lane = threadIdx.x & 63;
  const int gw   = (int)((blockIdx.x * 256 + threadIdx.x) >> 6); // 0..8191
  float lsum = 0.f;
  for (int tok = gw; tok < NTOK; tok += 8192) {
    const int ki = idx[tok];
    float4 xv = reinterpret_cast<const float4*>(x + (size_t)tok * D)[lane];
    float4 ev = reinterpret_cast<const float4*>(emb + (size_t)ki * D)[lane];
    float dx = ev.x - xv.x, dy = ev.y - xv.y, dz = ev.z - xv.z,
          dw = ev.w - xv.w;
    float4 q;
    q.x = xv.x + dx; q.y = xv.y + dy; q.z = xv.z + dz; q.w = xv.w + dw;
    reinterpret_cast<float4*>(qout + (size_t)tok * D)[lane] = q;
    lsum += dx * dx + dy * dy + dz * dz + dw * dw;
    float4* erow = reinterpret_cast<float4*>(enc + (size_t)tok * K);
    #pragma unroll
    for (int r = 0; r < 4; ++r) {
      const int fi = r * 64 + lane;
      float4 z;
      z.x = (fi * 4 + 0 == ki) ? 1.f : 0.f;
      z.y = (fi * 4 + 1 == ki) ? 1.f : 0.f;
      z.z = (fi * 4 + 2 == ki) ? 1.f : 0.f;
      z.w = (fi * 4 + 3 == ki) ? 1.f : 0.f;
      erow[fi] = z;
    }
    if (lane == 0) atomicAdd(&hist[ki], 1);
  }
  #pragma unroll
  for (int m = 1; m < 64; m <<= 1) lsum += __shfl_xor(lsum, m);
  __shared__ float wsum[4];
  if (lane == 0) wsum[threadIdx.x >> 6] = lsum;
  __syncthreads();
  if (threadIdx.x == 0) {
    double t = (double)wsum[0] + (double)wsum[1] + (double)wsum[2] +
               (double)wsum[3];
    atomicAdd(lossacc, t);
  }
}

// ---------------- kernel 3: finalize scalars ----------------
__global__ __launch_bounds__(256) void finalize_kernel(
    const int* __restrict__ hist, const double* __restrict__ lossacc,
    float* __restrict__ out_loss, float* __restrict__ out_perp) {
  const int lane = threadIdx.x & 63;
  float part = 0.f;
  for (int k = threadIdx.x; k < K; k += 256) {
    float p = (float)hist[k] * (1.0f / 65536.0f);
    part += p * logf(p + 1e-10f);
  }
  #pragma unroll
  for (int m = 1; m < 64; m <<= 1) part += __shfl_xor(part, m);
  __shared__ float wsum[4];
  if (lane == 0) wsum[threadIdx.x >> 6] = part;
  __syncthreads();
  if (threadIdx.x == 0) {
    float ent = wsum[0] + wsum[1] + wsum[2] + wsum[3];
    out_loss[0] = 0.25f * (float)(lossacc[0] * (1.0 / 16777216.0));
    out_perp[0] = expf(-ent);
  }
}

extern "C" void kernel_launch(void* const* d_in, const int* in_sizes, int n_in,
                              void* d_out, int out_size, void* d_ws,
                              size_t ws_size, hipStream_t stream) {
  const float* x   = (const float*)d_in[0];
  const float* emb = (const float*)d_in[1];
  float* out       = (float*)d_out;

  float* loss_out = out;                        // [0]
  float* q_out    = out + 1;                    // 16777216 elements
  float* perp_out = out + 1 + (size_t)NTOK * D; // [16777217]
  float* enc_out  = perp_out + 1;               // 67108864 elements

  char*   wsb  = (char*)d_ws;
  int*    idx  = (int*)wsb;                     // 65536 ints   @ 0
  float*  e2   = (float*)(wsb + 262144);        // 1024 f       @ 262144
  int*    hist = (int*)(wsb + 266240);          // 1024 int     @ 266240
  double* acc  = (double*)(wsb + 270336);       // 1 double     @ 270336

  // zero histogram + loss accumulator (ws is poisoned 0xAA before each call)
  hipMemsetAsync(wsb + 266240, 0, 8192, stream);

  e2_kernel<<<16, 256, 0, stream>>>(emb, e2);
  argmin_kernel<<<NTOK / 64, 256, 0, stream>>>(x, emb, e2, idx);
  output_kernel<<<2048, 256, 0, stream>>>(x, emb, idx, q_out, enc_out, hist,
                                          acc);
  finalize_kernel<<<1, 256, 0, stream>>>(hist, acc, loss_out, perp_out);
}

// Round 5
// 894.829 us; speedup vs baseline: 8.3389x; 1.2525x over previous
//
#include <hip/hip_runtime.h>
#include <hip/hip_bf16.h>

// VQ-VAE vector quantizer forward, MI355X.
// inputs:  d_in[0] = inputs  [128*512*256] f32  (N=65536 tokens x D=256)
//          d_in[1] = embedding [1024*256] f32   (K=1024 codes x D=256)
// outputs (concat f32): [0] vq_loss | [1..16777216] quantized_st |
//          [16777217] perplexity | [16777218..] encodings one-hot [65536*1024]

constexpr int NTOK = 65536;
constexpr int D    = 256;
constexpr int K    = 1024;

// ---------------- kernel 0: ||e_k||^2 ----------------
__global__ __launch_bounds__(256) void e2_kernel(
    const float* __restrict__ emb, float* __restrict__ e2) {
  const int lane = threadIdx.x & 63;
  const int gw   = (int)((blockIdx.x * blockDim.x + threadIdx.x) >> 6); // 64 waves
  for (int k = gw; k < K; k += 64) {
    float4 v = reinterpret_cast<const float4*>(emb + (size_t)k * D)[lane];
    float s = v.x * v.x + v.y * v.y + v.z * v.z + v.w * v.w;
    #pragma unroll
    for (int m = 1; m < 64; m <<= 1) s += __shfl_xor(s, m);
    if (lane == 0) e2[k] = s;
  }
}

// ---------------- kernel 1: tiled distance GEMM + fused argmin ----------------
// Block: 64 tokens x 1024 codes (16 chunks of 64 codes). 256 threads = 16x16,
// micro-tile 4 tokens x 4 codes. d-dimension processed in TWO halves of 128 so
// LDS = xs[128][64] + es[128][64] = 64 KB -> 2 blocks/CU (2 waves/SIMD): the
// second block covers ds_read latency + barrier drains (round-4: 1 block/CU
// gave VALUBusy 40%). x is re-staged per chunk-half from L2 (tile stays hot).
// dist = ||e||^2 - 2*dot (||x||^2 dropped: argmin-invariant per token).
// Strict < with ascending code order == jnp.argmin first-min tie-break.
__global__ __launch_bounds__(256, 2) void argmin_kernel(
    const float* __restrict__ x, const float* __restrict__ emb,
    const float* __restrict__ e2, int* __restrict__ out_idx) {
  __shared__ float xs[128 * 64];  // xT[d][t] for current d-half
  __shared__ float es[128 * 64];  // eT[d][c] for current d-half
  const int tid  = (int)threadIdx.x;
  const int tx   = tid & 15;   // code group within chunk  (codes tx*4..+3)
  const int ty   = tid >> 4;   // token group within block (tokens ty*4..+3)
  const int tok0 = (int)blockIdx.x * 64;
  const int t    = tid & 63;   // staging column 0..63
  const int g    = tid >> 6;   // staging wave 0..3

  float best[4];
  int   bidx[4];
  #pragma unroll
  for (int q = 0; q < 4; ++q) { best[q] = 3.4e38f; bidx[q] = 0; }

  for (int ch = 0; ch < 16; ++ch) {
    float acc[4][4];
    #pragma unroll
    for (int a = 0; a < 4; ++a)
      #pragma unroll
      for (int b = 0; b < 4; ++b) acc[a][b] = 0.f;

    #pragma unroll
    for (int dh = 0; dh < 2; ++dh) {
      __syncthreads();  // previous compute done before LDS overwrite
      // ---- stage x half-tile, transposed; writes hit banks t%32 -> 2-way
      //      (free). 8 float4 per thread. ----
      {
        const float4* xg = reinterpret_cast<const float4*>(x) +
                           (size_t)(tok0 + t) * 64 + dh * 32;
        #pragma unroll
        for (int p = 0; p < 8; ++p) {
          const int d4 = p * 4 + g;  // 0..31 within half
          float4 v = xg[d4];
          xs[(d4 * 4 + 0) * 64 + t] = v.x;
          xs[(d4 * 4 + 1) * 64 + t] = v.y;
          xs[(d4 * 4 + 2) * 64 + t] = v.z;
          xs[(d4 * 4 + 3) * 64 + t] = v.w;
        }
      }
      // ---- stage e half-chunk (64 codes), transposed ----
      {
        const float4* eg = reinterpret_cast<const float4*>(emb) +
                           (size_t)(ch * 64 + t) * 64 + dh * 32;
        #pragma unroll
        for (int p = 0; p < 8; ++p) {
          const int d4 = p * 4 + g;
          float4 v = eg[d4];
          es[(d4 * 4 + 0) * 64 + t] = v.x;
          es[(d4 * 4 + 1) * 64 + t] = v.y;
          es[(d4 * 4 + 2) * 64 + t] = v.z;
          es[(d4 * 4 + 3) * 64 + t] = v.w;
        }
      }
      __syncthreads();

      #pragma unroll 4
      for (int d = 0; d < 128; ++d) {
        const float4 xv =
            *reinterpret_cast<const float4*>(&xs[d * 64 + ty * 4]);
        const float4 ev =
            *reinterpret_cast<const float4*>(&es[d * 64 + tx * 4]);
        acc[0][0] = fmaf(xv.x, ev.x, acc[0][0]);
        acc[0][1] = fmaf(xv.x, ev.y, acc[0][1]);
        acc[0][2] = fmaf(xv.x, ev.z, acc[0][2]);
        acc[0][3] = fmaf(xv.x, ev.w, acc[0][3]);
        acc[1][0] = fmaf(xv.y, ev.x, acc[1][0]);
        acc[1][1] = fmaf(xv.y, ev.y, acc[1][1]);
        acc[1][2] = fmaf(xv.y, ev.z, acc[1][2]);
        acc[1][3] = fmaf(xv.y, ev.w, acc[1][3]);
        acc[2][0] = fmaf(xv.z, ev.x, acc[2][0]);
        acc[2][1] = fmaf(xv.z, ev.y, acc[2][1]);
        acc[2][2] = fmaf(xv.z, ev.z, acc[2][2]);
        acc[2][3] = fmaf(xv.z, ev.w, acc[2][3]);
        acc[3][0] = fmaf(xv.w, ev.x, acc[3][0]);
        acc[3][1] = fmaf(xv.w, ev.y, acc[3][1]);
        acc[3][2] = fmaf(xv.w, ev.z, acc[3][2]);
        acc[3][3] = fmaf(xv.w, ev.w, acc[3][3]);
      }
    }

    // fold distances, running argmin (ascending code order)
    #pragma unroll
    for (int j = 0; j < 4; ++j) {
      const int  code = ch * 64 + tx * 4 + j;
      const float e2v = e2[code];
      #pragma unroll
      for (int q = 0; q < 4; ++q) {
        const float dist = fmaf(-2.f, acc[q][j], e2v);
        if (dist < best[q]) { best[q] = dist; bidx[q] = code; }
      }
    }
  }

  // cross-tx reduction: 16-lane groups, (dist, idx) with first-min tie-break
  #pragma unroll
  for (int m = 1; m < 16; m <<= 1) {
    #pragma unroll
    for (int q = 0; q < 4; ++q) {
      const float ob = __shfl_xor(best[q], m);
      const int   oi = __shfl_xor(bidx[q], m);
      if (ob < best[q] || (ob == best[q] && oi < bidx[q])) {
        best[q] = ob;
        bidx[q] = oi;
      }
    }
  }
  if (tx == 0) {
    #pragma unroll
    for (int q = 0; q < 4; ++q) out_idx[tok0 + ty * 4 + q] = bidx[q];
  }
}

// ---------------- kernel 2: gather + one-hot + loss partials + histogram ----
// One wave per token (grid-stride): 64 lanes x float4 = 256 floats per row.
__global__ __launch_bounds__(256) void output_kernel(
    const float* __restrict__ x, const float* __restrict__ emb,
    const int* __restrict__ idx, float* __restrict__ qout,
    float* __restrict__ enc, int* __restrict__ hist,
    double* __restrict__ lossacc) {
  const int lane = threadIdx.x & 63;
  const int gw   = (int)((blockIdx.x * 256 + threadIdx.x) >> 6); // 0..16383
  float lsum = 0.f;
  for (int tok = gw; tok < NTOK; tok += 16384) {
    const int ki = idx[tok];
    float4 xv = reinterpret_cast<const float4*>(x + (size_t)tok * D)[lane];
    float4 ev = reinterpret_cast<const float4*>(emb + (size_t)ki * D)[lane];
    float dx = ev.x - xv.x, dy = ev.y - xv.y, dz = ev.z - xv.z,
          dw = ev.w - xv.w;
    float4 q;
    q.x = xv.x + dx; q.y = xv.y + dy; q.z = xv.z + dz; q.w = xv.w + dw;
    reinterpret_cast<float4*>(qout + (size_t)tok * D)[lane] = q;
    lsum += dx * dx + dy * dy + dz * dz + dw * dw;
    float4* erow = reinterpret_cast<float4*>(enc + (size_t)tok * K);
    #pragma unroll
    for (int r = 0; r < 4; ++r) {
      const int fi = r * 64 + lane;
      float4 z;
      z.x = (fi * 4 + 0 == ki) ? 1.f : 0.f;
      z.y = (fi * 4 + 1 == ki) ? 1.f : 0.f;
      z.z = (fi * 4 + 2 == ki) ? 1.f : 0.f;
      z.w = (fi * 4 + 3 == ki) ? 1.f : 0.f;
      erow[fi] = z;
    }
    if (lane == 0) atomicAdd(&hist[ki], 1);
  }
  #pragma unroll
  for (int m = 1; m < 64; m <<= 1) lsum += __shfl_xor(lsum, m);
  __shared__ float wsum[4];
  if (lane == 0) wsum[threadIdx.x >> 6] = lsum;
  __syncthreads();
  if (threadIdx.x == 0) {
    double tt = (double)wsum[0] + (double)wsum[1] + (double)wsum[2] +
                (double)wsum[3];
    atomicAdd(lossacc, tt);
  }
}

// ---------------- kernel 3: finalize scalars ----------------
__global__ __launch_bounds__(256) void finalize_kernel(
    const int* __restrict__ hist, const double* __restrict__ lossacc,
    float* __restrict__ out_loss, float* __restrict__ out_perp) {
  const int lane = threadIdx.x & 63;
  float part = 0.f;
  for (int k = threadIdx.x; k < K; k += 256) {
    float p = (float)hist[k] * (1.0f / 65536.0f);
    part += p * logf(p + 1e-10f);
  }
  #pragma unroll
  for (int m = 1; m < 64; m <<= 1) part += __shfl_xor(part, m);
  __shared__ float wsum[4];
  if (lane == 0) wsum[threadIdx.x >> 6] = part;
  __syncthreads();
  if (threadIdx.x == 0) {
    float ent = wsum[0] + wsum[1] + wsum[2] + wsum[3];
    out_loss[0] = 0.25f * (float)(lossacc[0] * (1.0 / 16777216.0));
    out_perp[0] = expf(-ent);
  }
}

extern "C" void kernel_launch(void* const* d_in, const int* in_sizes, int n_in,
                              void* d_out, int out_size, void* d_ws,
                              size_t ws_size, hipStream_t stream) {
  const float* x   = (const float*)d_in[0];
  const float* emb = (const float*)d_in[1];
  float* out       = (float*)d_out;

  float* loss_out = out;                        // [0]
  float* q_out    = out + 1;                    // 16777216 elements
  float* perp_out = out + 1 + (size_t)NTOK * D; // [16777217]
  float* enc_out  = perp_out + 1;               // 67108864 elements

  char*   wsb  = (char*)d_ws;
  int*    idx  = (int*)wsb;                     // 65536 ints   @ 0
  float*  e2   = (float*)(wsb + 262144);        // 1024 f       @ 262144
  int*    hist = (int*)(wsb + 266240);          // 1024 int     @ 266240
  double* acc  = (double*)(wsb + 270336);       // 1 double     @ 270336

  // zero histogram + loss accumulator (ws is poisoned 0xAA before each call)
  hipMemsetAsync(wsb + 266240, 0, 8192, stream);

  e2_kernel<<<16, 256, 0, stream>>>(emb, e2);
  argmin_kernel<<<NTOK / 64, 256, 0, stream>>>(x, emb, e2, idx);
  output_kernel<<<4096, 256, 0, stream>>>(x, emb, idx, q_out, enc_out, hist,
                                          acc);
  finalize_kernel<<<1, 256, 0, stream>>>(hist, acc, loss_out, perp_out);
}